// Round 2
// baseline (1350.456 us; speedup 1.0000x reference)
//
#include <hip/hip_runtime.h>
#include <hip/hip_bf16.h>
#include <math.h>

#define T_TOK 16384
#define DIM 768
#define NE 8
#define HID 3072
#define PADT 33792   // 32768 + 8*128 max padded pair rows
#define CHUNK 8192   // hbuf ring rows
#define NCHUNK 5     // ceil(PADT/CHUNK)

typedef unsigned short u16;
typedef __attribute__((ext_vector_type(8))) short bf16x8;
typedef __attribute__((ext_vector_type(4))) float f32x4;

__device__ __forceinline__ u16 f2bf(float f) {
  union { float f; unsigned u; } v; v.f = f;
  unsigned r = v.u + 0x7FFF + ((v.u >> 16) & 1);  // round-to-nearest-even
  return (u16)(r >> 16);
}

__device__ __forceinline__ float bf2f(u16 u) {
  union { unsigned u; float f; } v; v.u = ((unsigned)u) << 16; return v.f;
}

__device__ __forceinline__ void async16(void* lds, const void* g) {
  __builtin_amdgcn_global_load_lds((const __attribute__((address_space(1))) void*)g,
                                   (__attribute__((address_space(3))) void*)lds, 16, 0, 0);
}

// ---------------- x -> bf16 ----------------
__global__ __launch_bounds__(256) void cvt_x_kernel(const float* __restrict__ x,
                                                    u16* __restrict__ xb) {
  int i = blockIdx.x * 256 + threadIdx.x;
  if (i < T_TOK * DIM / 4) {
    float4 v = ((const float4*)x)[i];
    ushort4 o = make_ushort4(f2bf(v.x), f2bf(v.y), f2bf(v.z), f2bf(v.w));
    ((ushort4*)xb)[i] = o;
  }
}

// ---------------- transpose + cast: in [E][R][C] f32 -> out [E][C][R] bf16 ----------------
__global__ __launch_bounds__(256) void transpose_cvt(const float* __restrict__ in,
                                                     u16* __restrict__ outp, int R, int C) {
  __shared__ float tile[32][33];
  int e = blockIdx.z;
  int c0 = blockIdx.x * 32, r0 = blockIdx.y * 32;
  int tx = threadIdx.x & 31, ty = threadIdx.x >> 5;  // 32 x 8
  const float* ip = in + (size_t)e * R * C;
  u16* op = outp + (size_t)e * R * C;
#pragma unroll
  for (int i = 0; i < 4; ++i)
    tile[ty + i * 8][tx] = ip[(size_t)(r0 + ty + i * 8) * C + c0 + tx];
  __syncthreads();
#pragma unroll
  for (int i = 0; i < 4; ++i)
    op[(size_t)(c0 + ty + i * 8) * R + r0 + tx] = f2bf(tile[tx][ty + i * 8]);
}

// ---------------- router: fp32 logits, top-2, softmax ----------------
__global__ __launch_bounds__(256) void router_kernel(
    const float* __restrict__ x, const float* __restrict__ rw,
    const float* __restrict__ rb, int* __restrict__ idxb,
    float* __restrict__ wtb, int* __restrict__ counts) {
  __shared__ float rws[DIM * NE];
  for (int i = threadIdx.x; i < DIM * NE; i += 256) rws[i] = rw[i];
  __syncthreads();
  int lane = threadIdx.x & 63, wv = threadIdx.x >> 6;
  int t = blockIdx.x * 4 + wv;
  float acc[NE];
#pragma unroll
  for (int e = 0; e < NE; ++e) acc[e] = 0.f;
  const float* xr = x + (size_t)t * DIM;
  for (int i = 0; i < DIM / 64; ++i) {
    int d = lane + i * 64;
    float xv = xr[d];
#pragma unroll
    for (int e = 0; e < NE; ++e) acc[e] += xv * rws[d * NE + e];
  }
#pragma unroll
  for (int e = 0; e < NE; ++e)
    for (int off = 32; off; off >>= 1) acc[e] += __shfl_down(acc[e], off);
  if (lane == 0) {
    float lg[NE];
#pragma unroll
    for (int e = 0; e < NE; ++e) lg[e] = acc[e] + rb[e];
    int i0 = 0;
#pragma unroll
    for (int e = 1; e < NE; ++e) if (lg[e] > lg[i0]) i0 = e;  // first max wins ties (jax)
    int i1 = -1;
#pragma unroll
    for (int e = 0; e < NE; ++e)
      if (e != i0 && (i1 < 0 || lg[e] > lg[i1])) i1 = e;
    float ee = expf(lg[i1] - lg[i0]);          // <= 1
    float w0 = 1.f / (1.f + ee);
    float w1 = ee / (1.f + ee);
    idxb[t * 2] = i0; idxb[t * 2 + 1] = i1;
    wtb[t * 2] = w0; wtb[t * 2 + 1] = w1;
    atomicAdd(&counts[i0], 1);
    atomicAdd(&counts[i1], 1);
  }
}

// offsets are 128-padded so GEMM row-blocks never straddle experts
__global__ void scan_kernel(const int* __restrict__ counts, int* __restrict__ offsets,
                            int* __restrict__ cursors) {
  if (threadIdx.x == 0 && blockIdx.x == 0) {
    int o = 0;
    for (int e = 0; e < NE; ++e) {
      offsets[e] = o;
      o += (counts[e] + 127) & ~127;
      cursors[e] = 0;
    }
    offsets[NE] = o;  // total padded rows (<= PADT)
  }
}

__global__ __launch_bounds__(256) void scatter_kernel(
    const int* __restrict__ idxb, const int* __restrict__ offsets,
    int* __restrict__ cursors, int* __restrict__ g_tok, int* __restrict__ pairpos) {
  int t = blockIdx.x * 256 + threadIdx.x;
  if (t >= T_TOK) return;
  for (int k = 0; k < 2; ++k) {
    int e = idxb[t * 2 + k];
    int pos = atomicAdd(&cursors[e], 1);
    int pp = offsets[e] + pos;
    g_tok[pp] = t;
    pairpos[t * 2 + k] = pp;
  }
}

// ---------------- grouped GEMM1 (chunked): h = gelu(Xg @ W1 + b1), bf16 out ----------------
__global__ __launch_bounds__(256, 2) void gemm1_kernel(
    const u16* __restrict__ xb, const u16* __restrict__ w1t,
    const float* __restrict__ b1, const int* __restrict__ g_tok,
    const int* __restrict__ offsets, const int* __restrict__ counts,
    u16* __restrict__ hbuf, int g0) {
  const int g = g0 + blockIdx.x * 128;  // global padded pair-row base
  int e = -1;
#pragma unroll
  for (int i = 0; i < NE; ++i)
    if (g >= offsets[i] && g < offsets[i + 1]) e = i;
  if (e < 0) return;
  const int off = offsets[e];
  const int cnt = counts[e];
  const int r0 = g - off;
  if (r0 >= cnt) return;  // block entirely in pad zone
  const int n0 = blockIdx.y * 128;

  __shared__ u16 As[128 * 64];
  __shared__ u16 Bs[128 * 64];

  const int tid = threadIdx.x;
  const int lane = tid & 63;
  const int wv = tid >> 6;
  const int wr = wv >> 1, wc = wv & 1;  // 2x2 waves -> 64x64 each
  const int scol = (lane & 7) * 8;

  const u16* agp[4];
  const u16* bgp[4];
#pragma unroll
  for (int i = 0; i < 4; ++i) {
    int r = r0 + wv * 32 + i * 8 + (lane >> 3);
    int rr = r < cnt ? r : cnt - 1;
    int tok = g_tok[off + rr];
    agp[i] = xb + (size_t)tok * DIM + scol;
    int n = n0 + wv * 32 + i * 8 + (lane >> 3);
    bgp[i] = w1t + ((size_t)e * HID + n) * DIM + scol;
  }

  f32x4 acc[4][4];
#pragma unroll
  for (int i = 0; i < 4; ++i)
#pragma unroll
    for (int j = 0; j < 4; ++j) acc[i][j] = (f32x4){0.f, 0.f, 0.f, 0.f};

  for (int kt = 0; kt < DIM; kt += 64) {
#pragma unroll
    for (int i = 0; i < 4; ++i) {
      async16(&As[(wv * 32 + i * 8) * 64], agp[i] + kt);
      async16(&Bs[(wv * 32 + i * 8) * 64], bgp[i] + kt);
    }
    __syncthreads();
#pragma unroll
    for (int kk = 0; kk < 2; ++kk) {
      bf16x8 af[4], bfr[4];
#pragma unroll
      for (int i = 0; i < 4; ++i)
        af[i] = *(const bf16x8*)&As[(wr * 64 + i * 16 + (lane & 15)) * 64 + kk * 32 + (lane >> 4) * 8];
#pragma unroll
      for (int j = 0; j < 4; ++j)
        bfr[j] = *(const bf16x8*)&Bs[(wc * 64 + j * 16 + (lane & 15)) * 64 + kk * 32 + (lane >> 4) * 8];
#pragma unroll
      for (int i = 0; i < 4; ++i)
#pragma unroll
        for (int j = 0; j < 4; ++j)
          acc[i][j] = __builtin_amdgcn_mfma_f32_16x16x32_bf16(af[i], bfr[j], acc[i][j], 0, 0, 0);
    }
    __syncthreads();
  }

#pragma unroll
  for (int i = 0; i < 4; ++i) {
#pragma unroll
    for (int j = 0; j < 4; ++j) {
      int col = n0 + wc * 64 + j * 16 + (lane & 15);
      float bias = b1[e * HID + col];
#pragma unroll
      for (int rg = 0; rg < 4; ++rg) {
        int rloc = wr * 64 + i * 16 + (lane >> 4) * 4 + rg;
        if (r0 + rloc < cnt) {
          float v = acc[i][j][rg] + bias;
          v = 0.5f * v * (1.0f + erff(v * 0.70710678118f));  // exact GELU
          hbuf[(size_t)(g - g0 + rloc) * HID + col] = f2bf(v);
        }
      }
    }
  }
}

// ---------------- grouped GEMM2 (chunked): y = h @ W2 + b2, bf16 out ----------------
__global__ __launch_bounds__(256, 2) void gemm2_kernel(
    const u16* __restrict__ hbuf, const u16* __restrict__ w2t,
    const float* __restrict__ b2, const int* __restrict__ offsets,
    const int* __restrict__ counts, u16* __restrict__ ygb, int g0) {
  const int g = g0 + blockIdx.x * 128;
  int e = -1;
#pragma unroll
  for (int i = 0; i < NE; ++i)
    if (g >= offsets[i] && g < offsets[i + 1]) e = i;
  if (e < 0) return;
  const int off = offsets[e];
  const int cnt = counts[e];
  const int r0 = g - off;
  if (r0 >= cnt) return;
  const int n0 = blockIdx.y * 128;

  __shared__ u16 As[128 * 64];
  __shared__ u16 Bs[128 * 64];

  const int tid = threadIdx.x;
  const int lane = tid & 63;
  const int wv = tid >> 6;
  const int wr = wv >> 1, wc = wv & 1;
  const int scol = (lane & 7) * 8;

  const u16* agp[4];
  const u16* bgp[4];
#pragma unroll
  for (int i = 0; i < 4; ++i) {
    int r = r0 + wv * 32 + i * 8 + (lane >> 3);
    int rr = r < cnt ? r : cnt - 1;
    agp[i] = hbuf + (size_t)(off + rr - g0) * HID + scol;  // chunk-local row
    int n = n0 + wv * 32 + i * 8 + (lane >> 3);
    bgp[i] = w2t + ((size_t)e * DIM + n) * HID + scol;
  }

  f32x4 acc[4][4];
#pragma unroll
  for (int i = 0; i < 4; ++i)
#pragma unroll
    for (int j = 0; j < 4; ++j) acc[i][j] = (f32x4){0.f, 0.f, 0.f, 0.f};

  for (int kt = 0; kt < HID; kt += 64) {
#pragma unroll
    for (int i = 0; i < 4; ++i) {
      async16(&As[(wv * 32 + i * 8) * 64], agp[i] + kt);
      async16(&Bs[(wv * 32 + i * 8) * 64], bgp[i] + kt);
    }
    __syncthreads();
#pragma unroll
    for (int kk = 0; kk < 2; ++kk) {
      bf16x8 af[4], bfr[4];
#pragma unroll
      for (int i = 0; i < 4; ++i)
        af[i] = *(const bf16x8*)&As[(wr * 64 + i * 16 + (lane & 15)) * 64 + kk * 32 + (lane >> 4) * 8];
#pragma unroll
      for (int j = 0; j < 4; ++j)
        bfr[j] = *(const bf16x8*)&Bs[(wc * 64 + j * 16 + (lane & 15)) * 64 + kk * 32 + (lane >> 4) * 8];
#pragma unroll
      for (int i = 0; i < 4; ++i)
#pragma unroll
        for (int j = 0; j < 4; ++j)
          acc[i][j] = __builtin_amdgcn_mfma_f32_16x16x32_bf16(af[i], bfr[j], acc[i][j], 0, 0, 0);
    }
    __syncthreads();
  }

#pragma unroll
  for (int i = 0; i < 4; ++i) {
#pragma unroll
    for (int j = 0; j < 4; ++j) {
      int col = n0 + wc * 64 + j * 16 + (lane & 15);
      float bias = b2[e * DIM + col];
#pragma unroll
      for (int rg = 0; rg < 4; ++rg) {
        int rloc = wr * 64 + i * 16 + (lane >> 4) * 4 + rg;
        if (r0 + rloc < cnt)
          ygb[(size_t)(off + r0 + rloc) * DIM + col] = f2bf(acc[i][j][rg] + bias);
      }
    }
  }
}

// ---------------- combine + LayerNorm ----------------
__global__ __launch_bounds__(256) void combine_ln_kernel(
    const float* __restrict__ x, const u16* __restrict__ ygb,
    const int* __restrict__ pairpos, const float* __restrict__ wtb,
    const float* __restrict__ gamma, const float* __restrict__ beta,
    float* __restrict__ out) {
  int t = blockIdx.x;
  int p0 = pairpos[t * 2], p1 = pairpos[t * 2 + 1];
  float w0 = wtb[t * 2], w1 = wtb[t * 2 + 1];
  const float* xr = x + (size_t)t * DIM;
  const u16* y0 = ygb + (size_t)p0 * DIM;
  const u16* y1 = ygb + (size_t)p1 * DIM;
  float y[3];
  float s = 0.f, s2 = 0.f;
#pragma unroll
  for (int i = 0; i < 3; ++i) {
    int d = threadIdx.x + i * 256;
    float v = xr[d] + w0 * bf2f(y0[d]) + w1 * bf2f(y1[d]);
    y[i] = v; s += v; s2 += v * v;
  }
  for (int o = 32; o; o >>= 1) { s += __shfl_down(s, o); s2 += __shfl_down(s2, o); }
  __shared__ float red[8];
  int lane = threadIdx.x & 63, wv = threadIdx.x >> 6;
  if (lane == 0) { red[wv] = s; red[4 + wv] = s2; }
  __syncthreads();
  s = red[0] + red[1] + red[2] + red[3];
  s2 = red[4] + red[5] + red[6] + red[7];
  float mu = s * (1.f / DIM);
  float var = s2 * (1.f / DIM) - mu * mu;
  float inv = 1.f / sqrtf(var + 1e-5f);
#pragma unroll
  for (int i = 0; i < 3; ++i) {
    int d = threadIdx.x + i * 256;
    out[(size_t)t * DIM + d] = (y[i] - mu) * inv * gamma[d] + beta[d];
  }
}

extern "C" void kernel_launch(void* const* d_in, const int* in_sizes, int n_in,
                              void* d_out, int out_size, void* d_ws, size_t ws_size,
                              hipStream_t stream) {
  const float* x = (const float*)d_in[0];
  const float* rw = (const float*)d_in[1];
  const float* rb = (const float*)d_in[2];
  const float* w1 = (const float*)d_in[3];
  const float* b1 = (const float*)d_in[4];
  const float* w2 = (const float*)d_in[5];
  const float* b2 = (const float*)d_in[6];
  const float* gamma = (const float*)d_in[7];
  const float* beta = (const float*)d_in[8];
  float* out = (float*)d_out;

  char* p = (char*)d_ws;
  size_t o = 0;
  auto take = [&](size_t b) { void* q = (void*)(p + o); o += (b + 255) & ~((size_t)255); return q; };
  u16* xb = (u16*)take((size_t)T_TOK * DIM * 2);          // 25.2 MB
  u16* w1t = (u16*)take((size_t)NE * HID * DIM * 2);      // 37.7 MB
  u16* w2t = (u16*)take((size_t)NE * DIM * HID * 2);      // 37.7 MB
  u16* hbuf = (u16*)take((size_t)CHUNK * HID * 2);        // 50.3 MB (ring)
  u16* ygb = (u16*)take((size_t)PADT * DIM * 2);          // 51.9 MB
  int* g_tok = (int*)take((size_t)PADT * 4);
  int* pairpos = (int*)take((size_t)T_TOK * 2 * 4);
  int* idxb = (int*)take((size_t)T_TOK * 2 * 4);
  float* wtb = (float*)take((size_t)T_TOK * 2 * 4);
  int* counts = (int*)take(64);
  int* offsets = (int*)take(64);
  int* cursors = (int*)take(64);
  (void)in_sizes; (void)n_in; (void)out_size;

  if (o > ws_size) return;  // diagnostic: insufficient ws -> absmax ~5.34, not a crash

  hipMemsetAsync(counts, 0, NE * 4, stream);

  cvt_x_kernel<<<(T_TOK * DIM / 4 + 255) / 256, 256, 0, stream>>>(x, xb);
  transpose_cvt<<<dim3(HID / 32, DIM / 32, NE), 256, 0, stream>>>(w1, w1t, DIM, HID);
  transpose_cvt<<<dim3(DIM / 32, HID / 32, NE), 256, 0, stream>>>(w2, w2t, HID, DIM);
  router_kernel<<<T_TOK / 4, 256, 0, stream>>>(x, rw, rb, idxb, wtb, counts);
  scan_kernel<<<1, 64, 0, stream>>>(counts, offsets, cursors);
  scatter_kernel<<<T_TOK / 256, 256, 0, stream>>>(idxb, offsets, cursors, g_tok, pairpos);
  for (int c = 0; c < NCHUNK; ++c) {
    gemm1_kernel<<<dim3(CHUNK / 128, HID / 128), 256, 0, stream>>>(
        xb, w1t, b1, g_tok, offsets, counts, hbuf, c * CHUNK);
    gemm2_kernel<<<dim3(CHUNK / 128, DIM / 128), 256, 0, stream>>>(
        hbuf, w2t, b2, offsets, counts, ygb, c * CHUNK);
  }
  combine_ln_kernel<<<T_TOK, 256, 0, stream>>>(x, ygb, pairpos, wtb, gamma, beta, out);
}

// Round 3
// 863.997 us; speedup vs baseline: 1.5630x; 1.5630x over previous
//
#include <hip/hip_runtime.h>
#include <hip/hip_bf16.h>
#include <math.h>

#define T_TOK 16384
#define DIM 768
#define NE 8
#define HID 3072
#define PADT 33792   // 32768 + 8*128 max padded pair rows
#define CHUNK 8192   // hbuf ring rows
#define NCHUNK 5     // ceil(PADT/CHUNK)
#define NSLOT (T_TOK * 2)

typedef unsigned short u16;
typedef __attribute__((ext_vector_type(8))) short bf16x8;
typedef __attribute__((ext_vector_type(4))) float f32x4;

__device__ __forceinline__ u16 f2bf(float f) {
  union { float f; unsigned u; } v; v.f = f;
  unsigned r = v.u + 0x7FFF + ((v.u >> 16) & 1);  // round-to-nearest-even
  return (u16)(r >> 16);
}

__device__ __forceinline__ float bf2f(u16 u) {
  union { unsigned u; float f; } v; v.u = ((unsigned)u) << 16; return v.f;
}

__device__ __forceinline__ void async16(void* lds, const void* g) {
  __builtin_amdgcn_global_load_lds((const __attribute__((address_space(1))) void*)g,
                                   (__attribute__((address_space(3))) void*)lds, 16, 0, 0);
}

// ---------------- x -> bf16 ----------------
__global__ __launch_bounds__(256) void cvt_x_kernel(const float* __restrict__ x,
                                                    u16* __restrict__ xb) {
  int i = blockIdx.x * 256 + threadIdx.x;
  if (i < T_TOK * DIM / 4) {
    float4 v = ((const float4*)x)[i];
    ushort4 o = make_ushort4(f2bf(v.x), f2bf(v.y), f2bf(v.z), f2bf(v.w));
    ((ushort4*)xb)[i] = o;
  }
}

// ---------------- transpose + cast: in [E][R][C] f32 -> out [E][C][R] bf16 ----------------
__global__ __launch_bounds__(256) void transpose_cvt(const float* __restrict__ in,
                                                     u16* __restrict__ outp, int R, int C) {
  __shared__ float tile[32][33];
  int e = blockIdx.z;
  int c0 = blockIdx.x * 32, r0 = blockIdx.y * 32;
  int tx = threadIdx.x & 31, ty = threadIdx.x >> 5;  // 32 x 8
  const float* ip = in + (size_t)e * R * C;
  u16* op = outp + (size_t)e * R * C;
#pragma unroll
  for (int i = 0; i < 4; ++i)
    tile[ty + i * 8][tx] = ip[(size_t)(r0 + ty + i * 8) * C + c0 + tx];
  __syncthreads();
#pragma unroll
  for (int i = 0; i < 4; ++i)
    op[(size_t)(c0 + ty + i * 8) * R + r0 + tx] = f2bf(tile[tx][ty + i * 8]);
}

// ---------------- router: fp32 logits, top-2, softmax weights; NO atomics ----------------
// grid 512 x 256; each wave handles 8 tokens
__global__ __launch_bounds__(256) void router_kernel(
    const float* __restrict__ x, const float* __restrict__ rw,
    const float* __restrict__ rb, int* __restrict__ idxb,
    float* __restrict__ wtb) {
  __shared__ float rwt[NE * DIM];  // transposed [e][d], 24 KB
  for (int i = threadIdx.x; i < NE * DIM; i += 256) {
    int d = i >> 3, e = i & 7;
    rwt[e * DIM + d] = rw[i];
  }
  __syncthreads();
  int lane = threadIdx.x & 63, wv = threadIdx.x >> 6;
#pragma unroll 1
  for (int it = 0; it < 8; ++it) {
    int t = blockIdx.x * 32 + wv * 8 + it;
    const float4* xr = (const float4*)(x + (size_t)t * DIM);
    float acc[NE];
#pragma unroll
    for (int e = 0; e < NE; ++e) acc[e] = 0.f;
#pragma unroll
    for (int i = 0; i < 3; ++i) {
      float4 xv = xr[lane + i * 64];
#pragma unroll
      for (int e = 0; e < NE; ++e) {
        float4 w4 = ((const float4*)(rwt + e * DIM))[lane + i * 64];
        acc[e] += xv.x * w4.x + xv.y * w4.y + xv.z * w4.z + xv.w * w4.w;
      }
    }
#pragma unroll
    for (int e = 0; e < NE; ++e)
      for (int off = 32; off; off >>= 1) acc[e] += __shfl_down(acc[e], off);
    if (lane == 0) {
      float lg[NE];
#pragma unroll
      for (int e = 0; e < NE; ++e) lg[e] = acc[e] + rb[e];
      int i0 = 0;
#pragma unroll
      for (int e = 1; e < NE; ++e) if (lg[e] > lg[i0]) i0 = e;  // first max wins ties
      int i1 = -1;
#pragma unroll
      for (int e = 0; e < NE; ++e)
        if (e != i0 && (i1 < 0 || lg[e] > lg[i1])) i1 = e;
      float ee = expf(lg[i1] - lg[i0]);  // <= 1
      float w0 = 1.f / (1.f + ee);
      float w1 = ee / (1.f + ee);
      idxb[t * 2] = i0; idxb[t * 2 + 1] = i1;
      wtb[t * 2] = w0; wtb[t * 2 + 1] = w1;
    }
  }
}

// ---------------- counting sort, atomic-free ----------------
// 256 wavegroups x 128 slots. hist: per-wavegroup expert counts via ballot.
__global__ __launch_bounds__(256) void hist_kernel(const int* __restrict__ idxb,
                                                   int* __restrict__ whist) {
  int wv = threadIdx.x >> 6, lane = threadIdx.x & 63;
  int g = blockIdx.x * 4 + wv;  // 0..255
  int cnt = 0;                  // lane l<8 accumulates count of expert l
#pragma unroll
  for (int j = 0; j < 2; ++j) {
    int e = idxb[g * 128 + j * 64 + lane];
#pragma unroll
    for (int ex = 0; ex < NE; ++ex) {
      unsigned long long m = __ballot(e == ex);
      if (lane == ex) cnt += __popcll(m);
    }
  }
  if (lane < NE) whist[g * NE + lane] = cnt;
}

// single block: per-expert scan over wavegroups + 128-padded expert offsets
__global__ __launch_bounds__(256) void scan_kernel(const int* __restrict__ whist,
                                                   int* __restrict__ gbase,
                                                   int* __restrict__ offsets,
                                                   int* __restrict__ counts) {
  __shared__ int sgb[256 * NE];
  __shared__ int tot[NE], soff[NE + 1];
  int tid = threadIdx.x;
  if (tid < NE) {
    int run = 0;
    for (int g = 0; g < 256; ++g) { sgb[g * NE + tid] = run; run += whist[g * NE + tid]; }
    tot[tid] = run; counts[tid] = run;
  }
  __syncthreads();
  if (tid == 0) {
    int off = 0;
    for (int e = 0; e < NE; ++e) {
      soff[e] = off; offsets[e] = off;
      off += (tot[e] + 127) & ~127;
    }
    soff[NE] = off; offsets[NE] = off;
  }
  __syncthreads();
  for (int i = tid; i < 256 * NE; i += 256) gbase[i] = sgb[i] + soff[i & 7];
}

// ballot-prefix scatter; lanes 0..7 carry running cursors in registers
__global__ __launch_bounds__(256) void scatter_kernel(
    const int* __restrict__ idxb, const int* __restrict__ gbase,
    int* __restrict__ g_tok, int* __restrict__ pairpos) {
  int wv = threadIdx.x >> 6, lane = threadIdx.x & 63;
  int g = blockIdx.x * 4 + wv;
  int run = (lane < NE) ? gbase[g * NE + lane] : 0;
  unsigned long long ltm = (1ull << lane) - 1ull;
#pragma unroll
  for (int j = 0; j < 2; ++j) {
    int slot = g * 128 + j * 64 + lane;
    int e = idxb[slot];
    int myrank = 0;
#pragma unroll
    for (int ex = 0; ex < NE; ++ex) {
      unsigned long long m = __ballot(e == ex);
      int b = __shfl(run, ex);
      if (e == ex) myrank = b + __popcll(m & ltm);
      if (lane == ex) run += __popcll(m);
    }
    g_tok[myrank] = slot >> 1;
    pairpos[slot] = myrank;
  }
}

// ---------------- grouped GEMM1 (chunked): h = gelu(Xg @ W1 + b1), bf16 out ----------------
__global__ __launch_bounds__(256, 2) void gemm1_kernel(
    const u16* __restrict__ xb, const u16* __restrict__ w1t,
    const float* __restrict__ b1, const int* __restrict__ g_tok,
    const int* __restrict__ offsets, const int* __restrict__ counts,
    u16* __restrict__ hbuf, int g0) {
  const int g = g0 + blockIdx.x * 128;  // global padded pair-row base
  int e = -1;
#pragma unroll
  for (int i = 0; i < NE; ++i)
    if (g >= offsets[i] && g < offsets[i + 1]) e = i;
  if (e < 0) return;
  const int off = offsets[e];
  const int cnt = counts[e];
  const int r0 = g - off;
  if (r0 >= cnt) return;  // block entirely in pad zone
  const int n0 = blockIdx.y * 128;

  __shared__ u16 As[128 * 64];
  __shared__ u16 Bs[128 * 64];

  const int tid = threadIdx.x;
  const int lane = tid & 63;
  const int wv = tid >> 6;
  const int wr = wv >> 1, wc = wv & 1;  // 2x2 waves -> 64x64 each
  const int scol = (lane & 7) * 8;

  const u16* agp[4];
  const u16* bgp[4];
#pragma unroll
  for (int i = 0; i < 4; ++i) {
    int r = r0 + wv * 32 + i * 8 + (lane >> 3);
    int rr = r < cnt ? r : cnt - 1;
    int tok = g_tok[off + rr];
    agp[i] = xb + (size_t)tok * DIM + scol;
    int n = n0 + wv * 32 + i * 8 + (lane >> 3);
    bgp[i] = w1t + ((size_t)e * HID + n) * DIM + scol;
  }

  f32x4 acc[4][4];
#pragma unroll
  for (int i = 0; i < 4; ++i)
#pragma unroll
    for (int j = 0; j < 4; ++j) acc[i][j] = (f32x4){0.f, 0.f, 0.f, 0.f};

  for (int kt = 0; kt < DIM; kt += 64) {
#pragma unroll
    for (int i = 0; i < 4; ++i) {
      async16(&As[(wv * 32 + i * 8) * 64], agp[i] + kt);
      async16(&Bs[(wv * 32 + i * 8) * 64], bgp[i] + kt);
    }
    __syncthreads();
#pragma unroll
    for (int kk = 0; kk < 2; ++kk) {
      bf16x8 af[4], bfr[4];
#pragma unroll
      for (int i = 0; i < 4; ++i)
        af[i] = *(const bf16x8*)&As[(wr * 64 + i * 16 + (lane & 15)) * 64 + kk * 32 + (lane >> 4) * 8];
#pragma unroll
      for (int j = 0; j < 4; ++j)
        bfr[j] = *(const bf16x8*)&Bs[(wc * 64 + j * 16 + (lane & 15)) * 64 + kk * 32 + (lane >> 4) * 8];
#pragma unroll
      for (int i = 0; i < 4; ++i)
#pragma unroll
        for (int j = 0; j < 4; ++j)
          acc[i][j] = __builtin_amdgcn_mfma_f32_16x16x32_bf16(af[i], bfr[j], acc[i][j], 0, 0, 0);
    }
    __syncthreads();
  }

#pragma unroll
  for (int i = 0; i < 4; ++i) {
#pragma unroll
    for (int j = 0; j < 4; ++j) {
      int col = n0 + wc * 64 + j * 16 + (lane & 15);
      float bias = b1[e * HID + col];
#pragma unroll
      for (int rg = 0; rg < 4; ++rg) {
        int rloc = wr * 64 + i * 16 + (lane >> 4) * 4 + rg;
        if (r0 + rloc < cnt) {
          float v = acc[i][j][rg] + bias;
          v = 0.5f * v * (1.0f + erff(v * 0.70710678118f));  // exact GELU
          hbuf[(size_t)(g - g0 + rloc) * HID + col] = f2bf(v);
        }
      }
    }
  }
}

// ---------------- grouped GEMM2 (chunked): y = h @ W2 + b2, bf16 out ----------------
__global__ __launch_bounds__(256, 2) void gemm2_kernel(
    const u16* __restrict__ hbuf, const u16* __restrict__ w2t,
    const float* __restrict__ b2, const int* __restrict__ offsets,
    const int* __restrict__ counts, u16* __restrict__ ygb, int g0) {
  const int g = g0 + blockIdx.x * 128;
  int e = -1;
#pragma unroll
  for (int i = 0; i < NE; ++i)
    if (g >= offsets[i] && g < offsets[i + 1]) e = i;
  if (e < 0) return;
  const int off = offsets[e];
  const int cnt = counts[e];
  const int r0 = g - off;
  if (r0 >= cnt) return;
  const int n0 = blockIdx.y * 128;

  __shared__ u16 As[128 * 64];
  __shared__ u16 Bs[128 * 64];

  const int tid = threadIdx.x;
  const int lane = tid & 63;
  const int wv = tid >> 6;
  const int wr = wv >> 1, wc = wv & 1;
  const int scol = (lane & 7) * 8;

  const u16* agp[4];
  const u16* bgp[4];
#pragma unroll
  for (int i = 0; i < 4; ++i) {
    int r = r0 + wv * 32 + i * 8 + (lane >> 3);
    int rr = r < cnt ? r : cnt - 1;
    agp[i] = hbuf + (size_t)(off + rr - g0) * HID + scol;  // chunk-local row
    int n = n0 + wv * 32 + i * 8 + (lane >> 3);
    bgp[i] = w2t + ((size_t)e * DIM + n) * HID + scol;
  }

  f32x4 acc[4][4];
#pragma unroll
  for (int i = 0; i < 4; ++i)
#pragma unroll
    for (int j = 0; j < 4; ++j) acc[i][j] = (f32x4){0.f, 0.f, 0.f, 0.f};

  for (int kt = 0; kt < HID; kt += 64) {
#pragma unroll
    for (int i = 0; i < 4; ++i) {
      async16(&As[(wv * 32 + i * 8) * 64], agp[i] + kt);
      async16(&Bs[(wv * 32 + i * 8) * 64], bgp[i] + kt);
    }
    __syncthreads();
#pragma unroll
    for (int kk = 0; kk < 2; ++kk) {
      bf16x8 af[4], bfr[4];
#pragma unroll
      for (int i = 0; i < 4; ++i)
        af[i] = *(const bf16x8*)&As[(wr * 64 + i * 16 + (lane & 15)) * 64 + kk * 32 + (lane >> 4) * 8];
#pragma unroll
      for (int j = 0; j < 4; ++j)
        bfr[j] = *(const bf16x8*)&Bs[(wc * 64 + j * 16 + (lane & 15)) * 64 + kk * 32 + (lane >> 4) * 8];
#pragma unroll
      for (int i = 0; i < 4; ++i)
#pragma unroll
        for (int j = 0; j < 4; ++j)
          acc[i][j] = __builtin_amdgcn_mfma_f32_16x16x32_bf16(af[i], bfr[j], acc[i][j], 0, 0, 0);
    }
    __syncthreads();
  }

#pragma unroll
  for (int i = 0; i < 4; ++i) {
#pragma unroll
    for (int j = 0; j < 4; ++j) {
      int col = n0 + wc * 64 + j * 16 + (lane & 15);
      float bias = b2[e * DIM + col];
#pragma unroll
      for (int rg = 0; rg < 4; ++rg) {
        int rloc = wr * 64 + i * 16 + (lane >> 4) * 4 + rg;
        if (r0 + rloc < cnt)
          ygb[(size_t)(off + r0 + rloc) * DIM + col] = f2bf(acc[i][j][rg] + bias);
      }
    }
  }
}

// ---------------- combine + LayerNorm ----------------
__global__ __launch_bounds__(256) void combine_ln_kernel(
    const float* __restrict__ x, const u16* __restrict__ ygb,
    const int* __restrict__ pairpos, const float* __restrict__ wtb,
    const float* __restrict__ gamma, const float* __restrict__ beta,
    float* __restrict__ out) {
  int t = blockIdx.x;
  int p0 = pairpos[t * 2], p1 = pairpos[t * 2 + 1];
  float w0 = wtb[t * 2], w1 = wtb[t * 2 + 1];
  const float* xr = x + (size_t)t * DIM;
  const u16* y0 = ygb + (size_t)p0 * DIM;
  const u16* y1 = ygb + (size_t)p1 * DIM;
  float y[3];
  float s = 0.f, s2 = 0.f;
#pragma unroll
  for (int i = 0; i < 3; ++i) {
    int d = threadIdx.x + i * 256;
    float v = xr[d] + w0 * bf2f(y0[d]) + w1 * bf2f(y1[d]);
    y[i] = v; s += v; s2 += v * v;
  }
  for (int o = 32; o; o >>= 1) { s += __shfl_down(s, o); s2 += __shfl_down(s2, o); }
  __shared__ float red[8];
  int lane = threadIdx.x & 63, wv = threadIdx.x >> 6;
  if (lane == 0) { red[wv] = s; red[4 + wv] = s2; }
  __syncthreads();
  s = red[0] + red[1] + red[2] + red[3];
  s2 = red[4] + red[5] + red[6] + red[7];
  float mu = s * (1.f / DIM);
  float var = s2 * (1.f / DIM) - mu * mu;
  float inv = 1.f / sqrtf(var + 1e-5f);
#pragma unroll
  for (int i = 0; i < 3; ++i) {
    int d = threadIdx.x + i * 256;
    out[(size_t)t * DIM + d] = (y[i] - mu) * inv * gamma[d] + beta[d];
  }
}

extern "C" void kernel_launch(void* const* d_in, const int* in_sizes, int n_in,
                              void* d_out, int out_size, void* d_ws, size_t ws_size,
                              hipStream_t stream) {
  const float* x = (const float*)d_in[0];
  const float* rw = (const float*)d_in[1];
  const float* rb = (const float*)d_in[2];
  const float* w1 = (const float*)d_in[3];
  const float* b1 = (const float*)d_in[4];
  const float* w2 = (const float*)d_in[5];
  const float* b2 = (const float*)d_in[6];
  const float* gamma = (const float*)d_in[7];
  const float* beta = (const float*)d_in[8];
  float* out = (float*)d_out;

  char* p = (char*)d_ws;
  size_t o = 0;
  auto take = [&](size_t b) { void* q = (void*)(p + o); o += (b + 255) & ~((size_t)255); return q; };
  u16* xb = (u16*)take((size_t)T_TOK * DIM * 2);          // 25.2 MB
  u16* w1t = (u16*)take((size_t)NE * HID * DIM * 2);      // 37.7 MB
  u16* w2t = (u16*)take((size_t)NE * DIM * HID * 2);      // 37.7 MB
  u16* hbuf = (u16*)take((size_t)CHUNK * HID * 2);        // 50.3 MB (ring)
  u16* ygb = (u16*)take((size_t)PADT * DIM * 2);          // 51.9 MB
  int* g_tok = (int*)take((size_t)PADT * 4);
  int* pairpos = (int*)take((size_t)NSLOT * 4);
  int* idxb = (int*)take((size_t)NSLOT * 4);
  float* wtb = (float*)take((size_t)NSLOT * 4);
  int* whist = (int*)take((size_t)256 * NE * 4);
  int* gbase = (int*)take((size_t)256 * NE * 4);
  int* counts = (int*)take(64);
  int* offsets = (int*)take(64);
  (void)in_sizes; (void)n_in; (void)out_size;

  if (o > ws_size) return;  // diagnostic: insufficient ws -> wrong output, not a crash

  cvt_x_kernel<<<(T_TOK * DIM / 4 + 255) / 256, 256, 0, stream>>>(x, xb);
  transpose_cvt<<<dim3(HID / 32, DIM / 32, NE), 256, 0, stream>>>(w1, w1t, DIM, HID);
  transpose_cvt<<<dim3(DIM / 32, HID / 32, NE), 256, 0, stream>>>(w2, w2t, HID, DIM);
  router_kernel<<<512, 256, 0, stream>>>(x, rw, rb, idxb, wtb);
  hist_kernel<<<64, 256, 0, stream>>>(idxb, whist);
  scan_kernel<<<1, 256, 0, stream>>>(whist, gbase, offsets, counts);
  scatter_kernel<<<64, 256, 0, stream>>>(idxb, gbase, g_tok, pairpos);
  for (int c = 0; c < NCHUNK; ++c) {
    gemm1_kernel<<<dim3(CHUNK / 128, HID / 128), 256, 0, stream>>>(
        xb, w1t, b1, g_tok, offsets, counts, hbuf, c * CHUNK);
    gemm2_kernel<<<dim3(CHUNK / 128, DIM / 128), 256, 0, stream>>>(
        hbuf, w2t, b2, offsets, counts, ygb, c * CHUNK);
  }
  combine_ln_kernel<<<T_TOK, 256, 0, stream>>>(x, ygb, pairpos, wtb, gamma, beta, out);
}

// Round 4
// 684.503 us; speedup vs baseline: 1.9729x; 1.2622x over previous
//
#include <hip/hip_runtime.h>
#include <hip/hip_bf16.h>
#include <math.h>

#define T_TOK 16384
#define DIM 768
#define NE 8
#define HID 3072
#define PADT 33792   // 32768 + 8*128 max padded pair rows
#define CHUNK 8192   // hbuf ring rows
#define NCHUNK 5     // ceil(PADT/CHUNK)
#define NSLOT (T_TOK * 2)

typedef unsigned short u16;
typedef __attribute__((ext_vector_type(8))) short bf16x8;
typedef __attribute__((ext_vector_type(4))) float f32x4;

__device__ __forceinline__ u16 f2bf(float f) {
  union { float f; unsigned u; } v; v.f = f;
  unsigned r = v.u + 0x7FFF + ((v.u >> 16) & 1);  // round-to-nearest-even
  return (u16)(r >> 16);
}

__device__ __forceinline__ float bf2f(u16 u) {
  union { unsigned u; float f; } v; v.u = ((unsigned)u) << 16; return v.f;
}

__device__ __forceinline__ void async16(void* lds, const void* g) {
  __builtin_amdgcn_global_load_lds((const __attribute__((address_space(1))) void*)g,
                                   (__attribute__((address_space(3))) void*)lds, 16, 0, 0);
}

// exact-grade GELU: Abramowitz-Stegun 7.1.26 erf, |eps| <= 1.5e-7
__device__ __forceinline__ float gelu_f(float v) {
  float z = fabsf(v) * 0.70710678118f;
  float t = __builtin_amdgcn_rcpf(1.f + 0.3275911f * z);
  float p = t * (0.254829592f +
            t * (-0.284496736f +
            t * (1.421413741f +
            t * (-1.453152027f +
            t * 1.061405429f))));
  float e = __expf(-z * z);
  float erfz = fmaf(-p, e, 1.f);               // erf(|v|/sqrt2)
  float s = copysignf(erfz, v);
  return 0.5f * v * (1.f + s);
}

// ---------------- x -> bf16 ----------------
__global__ __launch_bounds__(256) void cvt_x_kernel(const float* __restrict__ x,
                                                    u16* __restrict__ xb) {
  int i = blockIdx.x * 256 + threadIdx.x;
  if (i < T_TOK * DIM / 4) {
    float4 v = ((const float4*)x)[i];
    ushort4 o = make_ushort4(f2bf(v.x), f2bf(v.y), f2bf(v.z), f2bf(v.w));
    ((ushort4*)xb)[i] = o;
  }
}

// ---------------- transpose + cast: in [E][R][C] f32 -> out [E][C][R] bf16 ----------------
__global__ __launch_bounds__(256) void transpose_cvt(const float* __restrict__ in,
                                                     u16* __restrict__ outp, int R, int C) {
  __shared__ float tile[32][33];
  int e = blockIdx.z;
  int c0 = blockIdx.x * 32, r0 = blockIdx.y * 32;
  int tx = threadIdx.x & 31, ty = threadIdx.x >> 5;  // 32 x 8
  const float* ip = in + (size_t)e * R * C;
  u16* op = outp + (size_t)e * R * C;
#pragma unroll
  for (int i = 0; i < 4; ++i)
    tile[ty + i * 8][tx] = ip[(size_t)(r0 + ty + i * 8) * C + c0 + tx];
  __syncthreads();
#pragma unroll
  for (int i = 0; i < 4; ++i)
    op[(size_t)(c0 + ty + i * 8) * R + r0 + tx] = f2bf(tile[tx][ty + i * 8]);
}

// ---------------- router: fp32 logits, top-2, softmax weights; NO atomics ----------------
__global__ __launch_bounds__(256) void router_kernel(
    const float* __restrict__ x, const float* __restrict__ rw,
    const float* __restrict__ rb, int* __restrict__ idxb,
    float* __restrict__ wtb) {
  __shared__ float rwt[NE * DIM];  // transposed [e][d], 24 KB
  for (int i = threadIdx.x; i < NE * DIM; i += 256) {
    int d = i >> 3, e = i & 7;
    rwt[e * DIM + d] = rw[i];
  }
  __syncthreads();
  int lane = threadIdx.x & 63, wv = threadIdx.x >> 6;
#pragma unroll 1
  for (int it = 0; it < 8; ++it) {
    int t = blockIdx.x * 32 + wv * 8 + it;
    const float4* xr = (const float4*)(x + (size_t)t * DIM);
    float acc[NE];
#pragma unroll
    for (int e = 0; e < NE; ++e) acc[e] = 0.f;
#pragma unroll
    for (int i = 0; i < 3; ++i) {
      float4 xv = xr[lane + i * 64];
#pragma unroll
      for (int e = 0; e < NE; ++e) {
        float4 w4 = ((const float4*)(rwt + e * DIM))[lane + i * 64];
        acc[e] += xv.x * w4.x + xv.y * w4.y + xv.z * w4.z + xv.w * w4.w;
      }
    }
#pragma unroll
    for (int e = 0; e < NE; ++e)
      for (int off = 32; off; off >>= 1) acc[e] += __shfl_down(acc[e], off);
    if (lane == 0) {
      float lg[NE];
#pragma unroll
      for (int e = 0; e < NE; ++e) lg[e] = acc[e] + rb[e];
      int i0 = 0;
#pragma unroll
      for (int e = 1; e < NE; ++e) if (lg[e] > lg[i0]) i0 = e;  // first max wins ties
      int i1 = -1;
#pragma unroll
      for (int e = 0; e < NE; ++e)
        if (e != i0 && (i1 < 0 || lg[e] > lg[i1])) i1 = e;
      float ee = expf(lg[i1] - lg[i0]);  // <= 1
      float w0 = 1.f / (1.f + ee);
      float w1 = ee / (1.f + ee);
      idxb[t * 2] = i0; idxb[t * 2 + 1] = i1;
      wtb[t * 2] = w0; wtb[t * 2 + 1] = w1;
    }
  }
}

// ---------------- counting sort, atomic-free ----------------
__global__ __launch_bounds__(256) void hist_kernel(const int* __restrict__ idxb,
                                                   int* __restrict__ whist) {
  int wv = threadIdx.x >> 6, lane = threadIdx.x & 63;
  int g = blockIdx.x * 4 + wv;  // 0..255
  int cnt = 0;
#pragma unroll
  for (int j = 0; j < 2; ++j) {
    int e = idxb[g * 128 + j * 64 + lane];
#pragma unroll
    for (int ex = 0; ex < NE; ++ex) {
      unsigned long long m = __ballot(e == ex);
      if (lane == ex) cnt += __popcll(m);
    }
  }
  if (lane < NE) whist[g * NE + lane] = cnt;
}

__global__ __launch_bounds__(256) void scan_kernel(const int* __restrict__ whist,
                                                   int* __restrict__ gbase,
                                                   int* __restrict__ offsets,
                                                   int* __restrict__ counts) {
  __shared__ int sgb[256 * NE];
  __shared__ int tot[NE], soff[NE + 1];
  int tid = threadIdx.x;
  if (tid < NE) {
    int run = 0;
    for (int g = 0; g < 256; ++g) { sgb[g * NE + tid] = run; run += whist[g * NE + tid]; }
    tot[tid] = run; counts[tid] = run;
  }
  __syncthreads();
  if (tid == 0) {
    int off = 0;
    for (int e = 0; e < NE; ++e) {
      soff[e] = off; offsets[e] = off;
      off += (tot[e] + 127) & ~127;
    }
    soff[NE] = off; offsets[NE] = off;
  }
  __syncthreads();
  for (int i = tid; i < 256 * NE; i += 256) gbase[i] = sgb[i] + soff[i & 7];
}

__global__ __launch_bounds__(256) void scatter_kernel(
    const int* __restrict__ idxb, const int* __restrict__ gbase,
    int* __restrict__ g_tok, int* __restrict__ pairpos) {
  int wv = threadIdx.x >> 6, lane = threadIdx.x & 63;
  int g = blockIdx.x * 4 + wv;
  int run = (lane < NE) ? gbase[g * NE + lane] : 0;
  unsigned long long ltm = (1ull << lane) - 1ull;
#pragma unroll
  for (int j = 0; j < 2; ++j) {
    int slot = g * 128 + j * 64 + lane;
    int e = idxb[slot];
    int myrank = 0;
#pragma unroll
    for (int ex = 0; ex < NE; ++ex) {
      unsigned long long m = __ballot(e == ex);
      int b = __shfl(run, ex);
      if (e == ex) myrank = b + __popcll(m & ltm);
      if (lane == ex) run += __popcll(m);
    }
    g_tok[myrank] = slot >> 1;
    pairpos[slot] = myrank;
  }
}

// ---------------- grouped GEMM1 (chunked): h = gelu(Xg @ W1 + b1), bf16 out ----------------
// T2 both-sides swizzle: linear LDS dest, XOR-permuted global source chunk,
// XOR-permuted ds_read chunk (rule #21: same involution on both sides).
__global__ __launch_bounds__(256, 2) void gemm1_kernel(
    const u16* __restrict__ xb, const u16* __restrict__ w1t,
    const float* __restrict__ b1, const int* __restrict__ g_tok,
    const int* __restrict__ offsets, const int* __restrict__ counts,
    u16* __restrict__ hbuf, int g0) {
  const int g = g0 + blockIdx.x * 128;  // global padded pair-row base
  int e = -1;
#pragma unroll
  for (int i = 0; i < NE; ++i)
    if (g >= offsets[i] && g < offsets[i + 1]) e = i;
  if (e < 0) return;
  const int off = offsets[e];
  const int cnt = counts[e];
  const int r0 = g - off;
  if (r0 >= cnt) return;  // block entirely in pad zone
  const int n0 = blockIdx.y * 128;

  __shared__ u16 As[128 * 64];
  __shared__ u16 Bs[128 * 64];

  const int tid = threadIdx.x;
  const int lane = tid & 63;
  const int wv = tid >> 6;
  const int wr = wv >> 1, wc = wv & 1;  // 2x2 waves -> 64x64 each
  // dest row&7 == lane>>3, dest chunk == lane&7 -> source chunk = (lane&7)^(lane>>3)
  const int scol = (((lane & 7) ^ (lane >> 3)) * 8);

  const u16* agp[4];
  const u16* bgp[4];
#pragma unroll
  for (int i = 0; i < 4; ++i) {
    int r = r0 + wv * 32 + i * 8 + (lane >> 3);
    int rr = r < cnt ? r : cnt - 1;
    int tok = g_tok[off + rr];
    agp[i] = xb + (size_t)tok * DIM + scol;
    int n = n0 + wv * 32 + i * 8 + (lane >> 3);
    bgp[i] = w1t + ((size_t)e * HID + n) * DIM + scol;
  }

  f32x4 acc[4][4];
#pragma unroll
  for (int i = 0; i < 4; ++i)
#pragma unroll
    for (int j = 0; j < 4; ++j) acc[i][j] = (f32x4){0.f, 0.f, 0.f, 0.f};

  for (int kt = 0; kt < DIM; kt += 64) {
#pragma unroll
    for (int i = 0; i < 4; ++i) {
      async16(&As[(wv * 32 + i * 8) * 64], agp[i] + kt);
      async16(&Bs[(wv * 32 + i * 8) * 64], bgp[i] + kt);
    }
    __syncthreads();
#pragma unroll
    for (int kk = 0; kk < 2; ++kk) {
      bf16x8 af[4], bfr[4];
#pragma unroll
      for (int i = 0; i < 4; ++i)
        af[i] = *(const bf16x8*)&As[(wr * 64 + i * 16 + (lane & 15)) * 64 +
                                    (((kk * 4 + (lane >> 4)) ^ (lane & 7)) * 8)];
#pragma unroll
      for (int j = 0; j < 4; ++j)
        bfr[j] = *(const bf16x8*)&Bs[(wc * 64 + j * 16 + (lane & 15)) * 64 +
                                     (((kk * 4 + (lane >> 4)) ^ (lane & 7)) * 8)];
#pragma unroll
      for (int i = 0; i < 4; ++i)
#pragma unroll
        for (int j = 0; j < 4; ++j)
          acc[i][j] = __builtin_amdgcn_mfma_f32_16x16x32_bf16(af[i], bfr[j], acc[i][j], 0, 0, 0);
    }
    __syncthreads();
  }

#pragma unroll
  for (int i = 0; i < 4; ++i) {
#pragma unroll
    for (int j = 0; j < 4; ++j) {
      int col = n0 + wc * 64 + j * 16 + (lane & 15);
      float bias = b1[e * HID + col];
#pragma unroll
      for (int rg = 0; rg < 4; ++rg) {
        int rloc = wr * 64 + i * 16 + (lane >> 4) * 4 + rg;
        if (r0 + rloc < cnt) {
          float v = gelu_f(acc[i][j][rg] + bias);
          hbuf[(size_t)(g - g0 + rloc) * HID + col] = f2bf(v);
        }
      }
    }
  }
}

// ---------------- grouped GEMM2 (chunked): y = h @ W2 + b2, bf16 out ----------------
__global__ __launch_bounds__(256, 2) void gemm2_kernel(
    const u16* __restrict__ hbuf, const u16* __restrict__ w2t,
    const float* __restrict__ b2, const int* __restrict__ offsets,
    const int* __restrict__ counts, u16* __restrict__ ygb, int g0) {
  const int g = g0 + blockIdx.x * 128;
  int e = -1;
#pragma unroll
  for (int i = 0; i < NE; ++i)
    if (g >= offsets[i] && g < offsets[i + 1]) e = i;
  if (e < 0) return;
  const int off = offsets[e];
  const int cnt = counts[e];
  const int r0 = g - off;
  if (r0 >= cnt) return;
  const int n0 = blockIdx.y * 128;

  __shared__ u16 As[128 * 64];
  __shared__ u16 Bs[128 * 64];

  const int tid = threadIdx.x;
  const int lane = tid & 63;
  const int wv = tid >> 6;
  const int wr = wv >> 1, wc = wv & 1;
  const int scol = (((lane & 7) ^ (lane >> 3)) * 8);

  const u16* agp[4];
  const u16* bgp[4];
#pragma unroll
  for (int i = 0; i < 4; ++i) {
    int r = r0 + wv * 32 + i * 8 + (lane >> 3);
    int rr = r < cnt ? r : cnt - 1;
    agp[i] = hbuf + (size_t)(off + rr - g0) * HID + scol;  // chunk-local row
    int n = n0 + wv * 32 + i * 8 + (lane >> 3);
    bgp[i] = w2t + ((size_t)e * DIM + n) * HID + scol;
  }

  f32x4 acc[4][4];
#pragma unroll
  for (int i = 0; i < 4; ++i)
#pragma unroll
    for (int j = 0; j < 4; ++j) acc[i][j] = (f32x4){0.f, 0.f, 0.f, 0.f};

  for (int kt = 0; kt < HID; kt += 64) {
#pragma unroll
    for (int i = 0; i < 4; ++i) {
      async16(&As[(wv * 32 + i * 8) * 64], agp[i] + kt);
      async16(&Bs[(wv * 32 + i * 8) * 64], bgp[i] + kt);
    }
    __syncthreads();
#pragma unroll
    for (int kk = 0; kk < 2; ++kk) {
      bf16x8 af[4], bfr[4];
#pragma unroll
      for (int i = 0; i < 4; ++i)
        af[i] = *(const bf16x8*)&As[(wr * 64 + i * 16 + (lane & 15)) * 64 +
                                    (((kk * 4 + (lane >> 4)) ^ (lane & 7)) * 8)];
#pragma unroll
      for (int j = 0; j < 4; ++j)
        bfr[j] = *(const bf16x8*)&Bs[(wc * 64 + j * 16 + (lane & 15)) * 64 +
                                     (((kk * 4 + (lane >> 4)) ^ (lane & 7)) * 8)];
#pragma unroll
      for (int i = 0; i < 4; ++i)
#pragma unroll
        for (int j = 0; j < 4; ++j)
          acc[i][j] = __builtin_amdgcn_mfma_f32_16x16x32_bf16(af[i], bfr[j], acc[i][j], 0, 0, 0);
    }
    __syncthreads();
  }

#pragma unroll
  for (int i = 0; i < 4; ++i) {
#pragma unroll
    for (int j = 0; j < 4; ++j) {
      int col = n0 + wc * 64 + j * 16 + (lane & 15);
      float bias = b2[e * DIM + col];
#pragma unroll
      for (int rg = 0; rg < 4; ++rg) {
        int rloc = wr * 64 + i * 16 + (lane >> 4) * 4 + rg;
        if (r0 + rloc < cnt)
          ygb[(size_t)(off + r0 + rloc) * DIM + col] = f2bf(acc[i][j][rg] + bias);
      }
    }
  }
}

// ---------------- combine + LayerNorm ----------------
__global__ __launch_bounds__(256) void combine_ln_kernel(
    const float* __restrict__ x, const u16* __restrict__ ygb,
    const int* __restrict__ pairpos, const float* __restrict__ wtb,
    const float* __restrict__ gamma, const float* __restrict__ beta,
    float* __restrict__ out) {
  int t = blockIdx.x;
  int p0 = pairpos[t * 2], p1 = pairpos[t * 2 + 1];
  float w0 = wtb[t * 2], w1 = wtb[t * 2 + 1];
  const float* xr = x + (size_t)t * DIM;
  const u16* y0 = ygb + (size_t)p0 * DIM;
  const u16* y1 = ygb + (size_t)p1 * DIM;
  float y[3];
  float s = 0.f, s2 = 0.f;
#pragma unroll
  for (int i = 0; i < 3; ++i) {
    int d = threadIdx.x + i * 256;
    float v = xr[d] + w0 * bf2f(y0[d]) + w1 * bf2f(y1[d]);
    y[i] = v; s += v; s2 += v * v;
  }
  for (int o = 32; o; o >>= 1) { s += __shfl_down(s, o); s2 += __shfl_down(s2, o); }
  __shared__ float red[8];
  int lane = threadIdx.x & 63, wv = threadIdx.x >> 6;
  if (lane == 0) { red[wv] = s; red[4 + wv] = s2; }
  __syncthreads();
  s = red[0] + red[1] + red[2] + red[3];
  s2 = red[4] + red[5] + red[6] + red[7];
  float mu = s * (1.f / DIM);
  float var = s2 * (1.f / DIM) - mu * mu;
  float inv = 1.f / sqrtf(var + 1e-5f);
#pragma unroll
  for (int i = 0; i < 3; ++i) {
    int d = threadIdx.x + i * 256;
    out[(size_t)t * DIM + d] = (y[i] - mu) * inv * gamma[d] + beta[d];
  }
}

extern "C" void kernel_launch(void* const* d_in, const int* in_sizes, int n_in,
                              void* d_out, int out_size, void* d_ws, size_t ws_size,
                              hipStream_t stream) {
  const float* x = (const float*)d_in[0];
  const float* rw = (const float*)d_in[1];
  const float* rb = (const float*)d_in[2];
  const float* w1 = (const float*)d_in[3];
  const float* b1 = (const float*)d_in[4];
  const float* w2 = (const float*)d_in[5];
  const float* b2 = (const float*)d_in[6];
  const float* gamma = (const float*)d_in[7];
  const float* beta = (const float*)d_in[8];
  float* out = (float*)d_out;

  char* p = (char*)d_ws;
  size_t o = 0;
  auto take = [&](size_t b) { void* q = (void*)(p + o); o += (b + 255) & ~((size_t)255); return q; };
  u16* xb = (u16*)take((size_t)T_TOK * DIM * 2);          // 25.2 MB
  u16* w1t = (u16*)take((size_t)NE * HID * DIM * 2);      // 37.7 MB
  u16* w2t = (u16*)take((size_t)NE * DIM * HID * 2);      // 37.7 MB
  u16* hbuf = (u16*)take((size_t)CHUNK * HID * 2);        // 50.3 MB (ring)
  u16* ygb = (u16*)take((size_t)PADT * DIM * 2);          // 51.9 MB
  int* g_tok = (int*)take((size_t)PADT * 4);
  int* pairpos = (int*)take((size_t)NSLOT * 4);
  int* idxb = (int*)take((size_t)NSLOT * 4);
  float* wtb = (float*)take((size_t)NSLOT * 4);
  int* whist = (int*)take((size_t)256 * NE * 4);
  int* gbase = (int*)take((size_t)256 * NE * 4);
  int* counts = (int*)take(64);
  int* offsets = (int*)take(64);
  (void)in_sizes; (void)n_in; (void)out_size;

  if (o > ws_size) return;  // diagnostic: insufficient ws -> wrong output, not a crash

  cvt_x_kernel<<<(T_TOK * DIM / 4 + 255) / 256, 256, 0, stream>>>(x, xb);
  transpose_cvt<<<dim3(HID / 32, DIM / 32, NE), 256, 0, stream>>>(w1, w1t, DIM, HID);
  transpose_cvt<<<dim3(DIM / 32, HID / 32, NE), 256, 0, stream>>>(w2, w2t, HID, DIM);
  router_kernel<<<512, 256, 0, stream>>>(x, rw, rb, idxb, wtb);
  hist_kernel<<<64, 256, 0, stream>>>(idxb, whist);
  scan_kernel<<<1, 256, 0, stream>>>(whist, gbase, offsets, counts);
  scatter_kernel<<<64, 256, 0, stream>>>(idxb, gbase, g_tok, pairpos);
  for (int c = 0; c < NCHUNK; ++c) {
    gemm1_kernel<<<dim3(CHUNK / 128, HID / 128), 256, 0, stream>>>(
        xb, w1t, b1, g_tok, offsets, counts, hbuf, c * CHUNK);
    gemm2_kernel<<<dim3(CHUNK / 128, DIM / 128), 256, 0, stream>>>(
        hbuf, w2t, b2, offsets, counts, ygb, c * CHUNK);
  }
  combine_ln_kernel<<<T_TOK, 256, 0, stream>>>(x, ygb, pairpos, wtb, gamma, beta, out);
}